// Round 2
// baseline (292.304 us; speedup 1.0000x reference)
//
#include <hip/hip_runtime.h>
#include <hip/hip_bf16.h>
#include <stdint.h>
#include <math.h>

#define N_NODES 8192
#define FDIM 128
#define LRELU_ALPHA 0.2f
#define BETA 0.3f
#define NEGV -9000000000000000.0f
#define THR 8.0f

typedef __attribute__((ext_vector_type(8))) short bf16x8;
typedef __attribute__((ext_vector_type(4))) float f32x4;

__device__ __forceinline__ uint16_t f2b(float x) {
  union { float f; uint32_t u; } v; v.f = x;
  uint32_t r = v.u + 0x7FFFu + ((v.u >> 16) & 1u);
  return (uint16_t)(r >> 16);
}

// ---------------------------------------------------------------------------
// prep_wh: Wh = h @ w.  Writes Wh fp32, Wh bf16 (row-major), Wh^T bf16.
// ---------------------------------------------------------------------------
__global__ void __launch_bounds__(256) prep_wh(
    const float* __restrict__ h, const float* __restrict__ w,
    float* __restrict__ whf, uint16_t* __restrict__ whb,
    uint16_t* __restrict__ whtb) {
  __shared__ float hs[32][128];
  const int t = threadIdx.x;
  const int rb = blockIdx.x * 32;
#pragma unroll
  for (int k = 0; k < 16; ++k) {
    int idx = t + k * 256;
    int r = idx >> 7, c = idx & 127;
    hs[r][c] = h[(size_t)(rb + r) * FDIM + c];
  }
  __syncthreads();
  const int c = t & 127;
  const int half = t >> 7;
  const int r0 = half * 16;
  float acc[16];
#pragma unroll
  for (int k = 0; k < 16; ++k) acc[k] = 0.f;
  for (int kk = 0; kk < 128; ++kk) {
    float wv = w[kk * FDIM + c];
#pragma unroll
    for (int k = 0; k < 16; ++k) acc[k] += hs[r0 + k][kk] * wv;
  }
  uint16_t tb[16];
#pragma unroll
  for (int k = 0; k < 16; ++k) {
    int r = rb + r0 + k;
    whf[(size_t)r * FDIM + c] = acc[k];
    uint16_t b = f2b(acc[k]);
    whb[(size_t)r * FDIM + c] = b;
    tb[k] = b;
  }
  uint16_t* dst = whtb + (size_t)c * N_NODES + rb + r0;
  bf16x8 v0, v1;
#pragma unroll
  for (int k = 0; k < 8; ++k) { v0[k] = (short)tb[k]; v1[k] = (short)tb[k + 8]; }
  *(bf16x8*)(dst) = v0;
  *(bf16x8*)(dst + 8) = v1;
}

// ---------------------------------------------------------------------------
// prep_s1: s1[i] = dot(Wh[i], a1[i]);  a2 -> bf16.
// ---------------------------------------------------------------------------
__global__ void __launch_bounds__(256) prep_s1(
    const float* __restrict__ whf, const float* __restrict__ a,
    float* __restrict__ s1, uint16_t* __restrict__ a2b) {
  const int t = threadIdx.x;
  const int rb = blockIdx.x * 32;
  const int wv = t >> 6;
  const int lane = t & 63;
  const int r = rb + wv * 8 + (lane >> 3);
  const int c0 = (lane & 7) * 16;
  float s = 0.f;
#pragma unroll
  for (int k = 0; k < 16; ++k) {
    s += whf[(size_t)r * FDIM + c0 + k] * a[(size_t)r * 256 + c0 + k];
  }
  s += __shfl_xor(s, 1);
  s += __shfl_xor(s, 2);
  s += __shfl_xor(s, 4);
  if ((lane & 7) == 0) s1[r] = s;
#pragma unroll
  for (int k = 0; k < 16; ++k) {
    int idx = t + k * 256;
    int rr = idx >> 7, cc = idx & 127;
    a2b[(size_t)(rb + rr) * FDIM + cc] = f2b(a[(size_t)(rb + rr) * 256 + 128 + cc]);
  }
}

// ---------------------------------------------------------------------------
// gat_main: fused scores + mask + online softmax (defer-max) + PV + merge.
// grid 512 blocks (16 rows each) x 512 thr (8 waves, 8-way j-split).
// ---------------------------------------------------------------------------
__global__ void __launch_bounds__(512, 4) gat_main(
    const int* __restrict__ adj, const uint16_t* __restrict__ whb,
    const uint16_t* __restrict__ whtb, const uint16_t* __restrict__ a2b,
    const float* __restrict__ s1, const float* __restrict__ whf,
    float* __restrict__ out) {
  __shared__ float O_lds[8][16][128];                    // 64 KB
  __shared__ __align__(16) uint16_t plds[8][16][40];     // 10 KB, pitch 80B
  __shared__ float m_lds[8][16], l_lds[8][16];
  __shared__ float ew_lds[8][16], linv_lds[16];

  const int tid = threadIdx.x;
  const int wv = tid >> 6;
  const int lane = tid & 63;
  const int ln = lane & 15;
  const int lg = lane >> 4;
  const int ibase = blockIdx.x * 16;

  // a2 A-fragments for this block's 16 rows: lane ln=row, k-slices lg*8..
  bf16x8 af[4];
#pragma unroll
  for (int ks = 0; ks < 4; ++ks)
    af[ks] = *(const bf16x8*)(a2b + (size_t)(ibase + ln) * FDIM + ks * 32 + lg * 8);

  float s1v[4];
  const int* adjr[4];
#pragma unroll
  for (int r = 0; r < 4; ++r) {
    s1v[r] = s1[ibase + lg * 4 + r];
    adjr[r] = adj + (size_t)(ibase + lg * 4 + r) * N_NODES;
  }

  float mrun[4], lsum[4];   // lsum is PER-LANE partial; reduced once at end
#pragma unroll
  for (int r = 0; r < 4; ++r) { mrun[r] = -INFINITY; lsum[r] = 0.f; }
  f32x4 O[8];
#pragma unroll
  for (int ft = 0; ft < 8; ++ft) O[ft] = (f32x4){0.f, 0.f, 0.f, 0.f};

  const int j0 = wv * (N_NODES / 8);
  for (int jb = j0; jb < j0 + N_NODES / 8; jb += 32) {
    // adj for this chunk: row = lg*4+r, col = nt*16+ln
    int adjv[2][4];
#pragma unroll
    for (int nt = 0; nt < 2; ++nt)
#pragma unroll
      for (int r = 0; r < 4; ++r)
        adjv[nt][r] = adjr[r][jb + nt * 16 + ln];

    // S = a2_tile . Wh_chunk^T
    f32x4 sacc[2];
    sacc[0] = (f32x4){0.f, 0.f, 0.f, 0.f};
    sacc[1] = (f32x4){0.f, 0.f, 0.f, 0.f};
#pragma unroll
    for (int nt = 0; nt < 2; ++nt)
#pragma unroll
      for (int ks = 0; ks < 4; ++ks) {
        bf16x8 b = *(const bf16x8*)(whb + (size_t)(jb + nt * 16 + ln) * FDIM + ks * 32 + lg * 8);
        sacc[nt] = __builtin_amdgcn_mfma_f32_16x16x32_bf16(af[ks], b, sacc[nt], 0, 0, 0);
      }

    // e = mask(lrelu(s1 + S))
    float e[2][4];
#pragma unroll
    for (int nt = 0; nt < 2; ++nt)
#pragma unroll
      for (int r = 0; r < 4; ++r) {
        float v = s1v[r] + sacc[nt][r];
        v = (v > 0.f) ? v : LRELU_ALPHA * v;
        e[nt][r] = (adjv[nt][r] > 0) ? v : NEGV;
      }

    // defer-max: only rescale when some e exceeds mrun + THR
    bool upd = false;
#pragma unroll
    for (int r = 0; r < 4; ++r)
      upd |= (e[0][r] > mrun[r] + THR) || (e[1][r] > mrun[r] + THR);
    if (__any(upd)) {
      float mx[4];
#pragma unroll
      for (int r = 0; r < 4; ++r) mx[r] = fmaxf(e[0][r], e[1][r]);
#pragma unroll
      for (int off = 1; off <= 8; off <<= 1)
#pragma unroll
        for (int r = 0; r < 4; ++r) mx[r] = fmaxf(mx[r], __shfl_xor(mx[r], off));
#pragma unroll
      for (int r = 0; r < 4; ++r) {
        float mn = fmaxf(mrun[r], mx[r]);
        float al = __expf(mrun[r] - mn);     // -INF first time -> 0
        mrun[r] = mn;
        lsum[r] *= al;
#pragma unroll
        for (int ft = 0; ft < 8; ++ft) O[ft][r] *= al;
      }
    }

    // p = exp(e - m); accumulate per-lane l
    float p[2][4];
#pragma unroll
    for (int nt = 0; nt < 2; ++nt)
#pragma unroll
      for (int r = 0; r < 4; ++r) {
        p[nt][r] = __expf(e[nt][r] - mrun[r]);
        lsum[r] += p[nt][r];
      }

    // P -> LDS (bf16) re-layout into PV A-fragment (per-wave region, no barrier)
#pragma unroll
    for (int nt = 0; nt < 2; ++nt)
#pragma unroll
      for (int r = 0; r < 4; ++r)
        plds[wv][lg * 4 + r][nt * 16 + ln] = f2b(p[nt][r]);

    bf16x8 pa = *(const bf16x8*)&plds[wv][ln][lg * 8];

    // O += P (16x32) . Wh_chunk (32x128)
#pragma unroll
    for (int ft = 0; ft < 8; ++ft) {
      bf16x8 bv = *(const bf16x8*)(whtb + (size_t)(ft * 16 + ln) * N_NODES + jb + lg * 8);
      O[ft] = __builtin_amdgcn_mfma_f32_16x16x32_bf16(pa, bv, O[ft], 0, 0, 0);
    }
  }

  // final per-row l: reduce per-lane partials over the 16-lane group
#pragma unroll
  for (int off = 1; off <= 8; off <<= 1)
#pragma unroll
    for (int r = 0; r < 4; ++r) lsum[r] += __shfl_xor(lsum[r], off);

  if (ln == 0) {
#pragma unroll
    for (int r = 0; r < 4; ++r) {
      m_lds[wv][lg * 4 + r] = mrun[r];
      l_lds[wv][lg * 4 + r] = lsum[r];
    }
  }
#pragma unroll
  for (int ft = 0; ft < 8; ++ft)
#pragma unroll
    for (int r = 0; r < 4; ++r)
      O_lds[wv][lg * 4 + r][ft * 16 + ln] = O[ft][r];
  __syncthreads();

  if (tid < 16) {
    float ms = -INFINITY;
#pragma unroll
    for (int w2 = 0; w2 < 8; ++w2) ms = fmaxf(ms, m_lds[w2][tid]);
    float L = 0.f;
#pragma unroll
    for (int w2 = 0; w2 < 8; ++w2) {
      float x = __expf(m_lds[w2][tid] - ms);
      ew_lds[w2][tid] = x;
      L += l_lds[w2][tid] * x;
    }
    linv_lds[tid] = 1.0f / L;
  }
  __syncthreads();

#pragma unroll
  for (int k = 0; k < 4; ++k) {
    int idx = tid + k * 512;          // 0..2047 = 16 rows x 128
    int r = idx >> 7, f = idx & 127;
    float v = 0.f;
#pragma unroll
    for (int w2 = 0; w2 < 8; ++w2) v += O_lds[w2][r][f] * ew_lds[w2][r];
    v *= linv_lds[r];
    v += BETA * whf[(size_t)(ibase + r) * FDIM + f];
    out[(size_t)(ibase + r) * FDIM + f] = (v > 0.f) ? v : (__expf(v) - 1.0f);
  }
}

// ---------------------------------------------------------------------------
extern "C" void kernel_launch(void* const* d_in, const int* in_sizes, int n_in,
                              void* d_out, int out_size, void* d_ws, size_t ws_size,
                              hipStream_t stream) {
  const float* h   = (const float*)d_in[0];
  const int*   adj = (const int*)d_in[1];
  const float* w   = (const float*)d_in[3];
  const float* a   = (const float*)d_in[4];
  float* out = (float*)d_out;

  char* ws = (char*)d_ws;
  float*    whf  = (float*)ws;                     // 4 MB
  uint16_t* whb  = (uint16_t*)(ws + (4 << 20));    // 2 MB
  uint16_t* whtb = (uint16_t*)(ws + (6 << 20));    // 2 MB
  uint16_t* a2b  = (uint16_t*)(ws + (8 << 20));    // 2 MB
  float*    s1   = (float*)(ws + (10 << 20));      // 32 KB

  prep_wh<<<N_NODES / 32, 256, 0, stream>>>(h, w, whf, whb, whtb);
  prep_s1<<<N_NODES / 32, 256, 0, stream>>>(whf, a, s1, a2b);
  gat_main<<<N_NODES / 16, 512, 0, stream>>>(adj, whb, whtb, a2b, s1, whf, out);
}

// Round 3
// 168.619 us; speedup vs baseline: 1.7335x; 1.7335x over previous
//
#include <hip/hip_runtime.h>
#include <hip/hip_bf16.h>
#include <stdint.h>
#include <math.h>

#define N_NODES 8192
#define FDIM 128
#define LRELU_ALPHA 0.2f
#define BETA 0.3f
#define NEGV -9000000000000000.0f
#define THR 8.0f

typedef __attribute__((ext_vector_type(8))) short bf16x8;
typedef __attribute__((ext_vector_type(4))) float f32x4;

__device__ __forceinline__ uint16_t f2b(float x) {
  union { float f; uint32_t u; } v; v.f = x;
  uint32_t r = v.u + 0x7FFFu + ((v.u >> 16) & 1u);
  return (uint16_t)(r >> 16);
}

// ---------------------------------------------------------------------------
// prep_wh: Wh = h @ w.  Writes Wh fp32, Wh bf16 (row-major), Wh^T bf16.
// ---------------------------------------------------------------------------
__global__ void __launch_bounds__(256) prep_wh(
    const float* __restrict__ h, const float* __restrict__ w,
    float* __restrict__ whf, uint16_t* __restrict__ whb,
    uint16_t* __restrict__ whtb) {
  __shared__ float hs[32][128];
  const int t = threadIdx.x;
  const int rb = blockIdx.x * 32;
#pragma unroll
  for (int k = 0; k < 16; ++k) {
    int idx = t + k * 256;
    int r = idx >> 7, c = idx & 127;
    hs[r][c] = h[(size_t)(rb + r) * FDIM + c];
  }
  __syncthreads();
  const int c = t & 127;
  const int half = t >> 7;
  const int r0 = half * 16;
  float acc[16];
#pragma unroll
  for (int k = 0; k < 16; ++k) acc[k] = 0.f;
  for (int kk = 0; kk < 128; ++kk) {
    float wv = w[kk * FDIM + c];
#pragma unroll
    for (int k = 0; k < 16; ++k) acc[k] += hs[r0 + k][kk] * wv;
  }
  uint16_t tb[16];
#pragma unroll
  for (int k = 0; k < 16; ++k) {
    int r = rb + r0 + k;
    whf[(size_t)r * FDIM + c] = acc[k];
    uint16_t b = f2b(acc[k]);
    whb[(size_t)r * FDIM + c] = b;
    tb[k] = b;
  }
  uint16_t* dst = whtb + (size_t)c * N_NODES + rb + r0;
  bf16x8 v0, v1;
#pragma unroll
  for (int k = 0; k < 8; ++k) { v0[k] = (short)tb[k]; v1[k] = (short)tb[k + 8]; }
  *(bf16x8*)(dst) = v0;
  *(bf16x8*)(dst + 8) = v1;
}

// ---------------------------------------------------------------------------
// prep_s1: s1[i] = dot(Wh[i], a1[i]);  a2 -> bf16.
// ---------------------------------------------------------------------------
__global__ void __launch_bounds__(256) prep_s1(
    const float* __restrict__ whf, const float* __restrict__ a,
    float* __restrict__ s1, uint16_t* __restrict__ a2b) {
  const int t = threadIdx.x;
  const int rb = blockIdx.x * 32;
  const int wv = t >> 6;
  const int lane = t & 63;
  const int r = rb + wv * 8 + (lane >> 3);
  const int c0 = (lane & 7) * 16;
  float s = 0.f;
#pragma unroll
  for (int k = 0; k < 16; ++k) {
    s += whf[(size_t)r * FDIM + c0 + k] * a[(size_t)r * 256 + c0 + k];
  }
  s += __shfl_xor(s, 1);
  s += __shfl_xor(s, 2);
  s += __shfl_xor(s, 4);
  if ((lane & 7) == 0) s1[r] = s;
#pragma unroll
  for (int k = 0; k < 16; ++k) {
    int idx = t + k * 256;
    int rr = idx >> 7, cc = idx & 127;
    a2b[(size_t)(rb + rr) * FDIM + cc] = f2b(a[(size_t)(rb + rr) * 256 + 128 + cc]);
  }
}

// ---------------------------------------------------------------------------
// gat_main: ITILE=32 per block; 8 waves, 8-way j-split; each wave computes
// TWO 16-row MFMA tiles so every whb/whtb fragment load is used twice.
// grid 256 blocks x 512 thr.
// ---------------------------------------------------------------------------
__global__ void __launch_bounds__(512, 2) gat_main(
    const int* __restrict__ adj, const uint16_t* __restrict__ whb,
    const uint16_t* __restrict__ whtb, const uint16_t* __restrict__ a2b,
    const float* __restrict__ s1, const float* __restrict__ whf,
    float* __restrict__ out) {
  __shared__ float O_lds[8][16][128];                    // 64 KB (2-pass merge)
  __shared__ __align__(16) uint16_t plds[8][32][40];     // 20.5 KB, pitch 80B
  __shared__ float m_lds[8][32], l_lds[8][32];
  __shared__ float ew_lds[8][32], linv_lds[32];

  const int tid = threadIdx.x;
  const int wv = tid >> 6;
  const int lane = tid & 63;
  const int ln = lane & 15;
  const int lg = lane >> 4;
  const int ibase = blockIdx.x * 32;

  // a2 A-fragments for both 16-row i-tiles
  bf16x8 af[2][4];
#pragma unroll
  for (int it = 0; it < 2; ++it)
#pragma unroll
    for (int ks = 0; ks < 4; ++ks)
      af[it][ks] = *(const bf16x8*)(a2b + (size_t)(ibase + it * 16 + ln) * FDIM + ks * 32 + lg * 8);

  float s1v[2][4];
#pragma unroll
  for (int it = 0; it < 2; ++it)
#pragma unroll
    for (int r = 0; r < 4; ++r)
      s1v[it][r] = s1[ibase + it * 16 + lg * 4 + r];

  const int* adjbase = adj + (size_t)(ibase + lg * 4) * N_NODES + ln;

  float mrun[2][4], lsum[2][4];
#pragma unroll
  for (int it = 0; it < 2; ++it)
#pragma unroll
    for (int r = 0; r < 4; ++r) { mrun[it][r] = -INFINITY; lsum[it][r] = 0.f; }
  f32x4 O[2][8];
#pragma unroll
  for (int it = 0; it < 2; ++it)
#pragma unroll
    for (int ft = 0; ft < 8; ++ft) O[it][ft] = (f32x4){0.f, 0.f, 0.f, 0.f};

  const int j0 = wv * (N_NODES / 8);
  for (int jb = j0; jb < j0 + N_NODES / 8; jb += 32) {
    // adj: rows (it*16 + lg*4 + r), cols jb + nt*16 + ln
    int adjv[2][2][4];
#pragma unroll
    for (int it = 0; it < 2; ++it)
#pragma unroll
      for (int nt = 0; nt < 2; ++nt)
#pragma unroll
        for (int r = 0; r < 4; ++r)
          adjv[it][nt][r] = adjbase[(size_t)(it * 16 + r) * N_NODES + jb + nt * 16];

    // scores: B-fragment loaded once, fed to both i-tiles
    f32x4 sacc[2][2];
#pragma unroll
    for (int it = 0; it < 2; ++it)
#pragma unroll
      for (int nt = 0; nt < 2; ++nt) sacc[it][nt] = (f32x4){0.f, 0.f, 0.f, 0.f};
#pragma unroll
    for (int nt = 0; nt < 2; ++nt)
#pragma unroll
      for (int ks = 0; ks < 4; ++ks) {
        bf16x8 b = *(const bf16x8*)(whb + (size_t)(jb + nt * 16 + ln) * FDIM + ks * 32 + lg * 8);
        sacc[0][nt] = __builtin_amdgcn_mfma_f32_16x16x32_bf16(af[0][ks], b, sacc[0][nt], 0, 0, 0);
        sacc[1][nt] = __builtin_amdgcn_mfma_f32_16x16x32_bf16(af[1][ks], b, sacc[1][nt], 0, 0, 0);
      }

    // e = mask(lrelu(s1 + S))
    float e[2][2][4];
#pragma unroll
    for (int it = 0; it < 2; ++it)
#pragma unroll
      for (int nt = 0; nt < 2; ++nt)
#pragma unroll
        for (int r = 0; r < 4; ++r) {
          float v = s1v[it][r] + sacc[it][nt][r];
          v = (v > 0.f) ? v : LRELU_ALPHA * v;
          e[it][nt][r] = (adjv[it][nt][r] > 0) ? v : NEGV;
        }

    // defer-max
    bool upd = false;
#pragma unroll
    for (int it = 0; it < 2; ++it)
#pragma unroll
      for (int r = 0; r < 4; ++r)
        upd |= (e[it][0][r] > mrun[it][r] + THR) || (e[it][1][r] > mrun[it][r] + THR);
    if (__any(upd)) {
#pragma unroll
      for (int it = 0; it < 2; ++it) {
        float mx[4];
#pragma unroll
        for (int r = 0; r < 4; ++r) mx[r] = fmaxf(e[it][0][r], e[it][1][r]);
#pragma unroll
        for (int off = 1; off <= 8; off <<= 1)
#pragma unroll
          for (int r = 0; r < 4; ++r) mx[r] = fmaxf(mx[r], __shfl_xor(mx[r], off));
#pragma unroll
        for (int r = 0; r < 4; ++r) {
          float mn = fmaxf(mrun[it][r], mx[r]);
          float al = __expf(mrun[it][r] - mn);
          mrun[it][r] = mn;
          lsum[it][r] *= al;
#pragma unroll
          for (int ft = 0; ft < 8; ++ft) O[it][ft][r] *= al;
        }
      }
    }

    // p = exp(e - m); per-lane l partial; stash into plds
#pragma unroll
    for (int it = 0; it < 2; ++it)
#pragma unroll
      for (int nt = 0; nt < 2; ++nt)
#pragma unroll
        for (int r = 0; r < 4; ++r) {
          float p = __expf(e[it][nt][r] - mrun[it][r]);
          lsum[it][r] += p;
          plds[wv][it * 16 + lg * 4 + r][nt * 16 + ln] = f2b(p);
        }

    bf16x8 pa0 = *(const bf16x8*)&plds[wv][ln][lg * 8];
    bf16x8 pa1 = *(const bf16x8*)&plds[wv][16 + ln][lg * 8];

    // PV: B-fragment loaded once, fed to both i-tiles
#pragma unroll
    for (int ft = 0; ft < 8; ++ft) {
      bf16x8 bv = *(const bf16x8*)(whtb + (size_t)(ft * 16 + ln) * N_NODES + jb + lg * 8);
      O[0][ft] = __builtin_amdgcn_mfma_f32_16x16x32_bf16(pa0, bv, O[0][ft], 0, 0, 0);
      O[1][ft] = __builtin_amdgcn_mfma_f32_16x16x32_bf16(pa1, bv, O[1][ft], 0, 0, 0);
    }
  }

  // reduce per-lane l partials over the 16-lane group
#pragma unroll
  for (int off = 1; off <= 8; off <<= 1)
#pragma unroll
    for (int it = 0; it < 2; ++it)
#pragma unroll
      for (int r = 0; r < 4; ++r) lsum[it][r] += __shfl_xor(lsum[it][r], off);

  if (ln == 0) {
#pragma unroll
    for (int it = 0; it < 2; ++it)
#pragma unroll
      for (int r = 0; r < 4; ++r) {
        m_lds[wv][it * 16 + lg * 4 + r] = mrun[it][r];
        l_lds[wv][it * 16 + lg * 4 + r] = lsum[it][r];
      }
  }
  __syncthreads();

  if (tid < 32) {
    float ms = -INFINITY;
#pragma unroll
    for (int w2 = 0; w2 < 8; ++w2) ms = fmaxf(ms, m_lds[w2][tid]);
    float L = 0.f;
#pragma unroll
    for (int w2 = 0; w2 < 8; ++w2) {
      float x = __expf(m_lds[w2][tid] - ms);
      ew_lds[w2][tid] = x;
      L += l_lds[w2][tid] * x;
    }
    linv_lds[tid] = 1.0f / L;
  }
  __syncthreads();

  // two-pass merge: 16 rows at a time through the 64KB buffer
#pragma unroll
  for (int h = 0; h < 2; ++h) {
#pragma unroll
    for (int ft = 0; ft < 8; ++ft)
#pragma unroll
      for (int r = 0; r < 4; ++r)
        O_lds[wv][lg * 4 + r][ft * 16 + ln] = O[h][ft][r];
    __syncthreads();
#pragma unroll
    for (int k = 0; k < 4; ++k) {
      int idx = tid + k * 512;        // 0..2047 = 16 rows x 128
      int r = idx >> 7, f = idx & 127;
      float v = 0.f;
#pragma unroll
      for (int w2 = 0; w2 < 8; ++w2) v += O_lds[w2][r][f] * ew_lds[w2][h * 16 + r];
      v *= linv_lds[h * 16 + r];
      int row = ibase + h * 16 + r;
      v += BETA * whf[(size_t)row * FDIM + f];
      out[(size_t)row * FDIM + f] = (v > 0.f) ? v : (__expf(v) - 1.0f);
    }
    if (h == 0) __syncthreads();
  }
}

// ---------------------------------------------------------------------------
extern "C" void kernel_launch(void* const* d_in, const int* in_sizes, int n_in,
                              void* d_out, int out_size, void* d_ws, size_t ws_size,
                              hipStream_t stream) {
  const float* h   = (const float*)d_in[0];
  const int*   adj = (const int*)d_in[1];
  const float* w   = (const float*)d_in[3];
  const float* a   = (const float*)d_in[4];
  float* out = (float*)d_out;

  char* ws = (char*)d_ws;
  float*    whf  = (float*)ws;                     // 4 MB
  uint16_t* whb  = (uint16_t*)(ws + (4 << 20));    // 2 MB
  uint16_t* whtb = (uint16_t*)(ws + (6 << 20));    // 2 MB
  uint16_t* a2b  = (uint16_t*)(ws + (8 << 20));    // 2 MB
  float*    s1   = (float*)(ws + (10 << 20));      // 32 KB

  prep_wh<<<N_NODES / 32, 256, 0, stream>>>(h, w, whf, whb, whtb);
  prep_s1<<<N_NODES / 32, 256, 0, stream>>>(whf, a, s1, a2b);
  gat_main<<<N_NODES / 32, 512, 0, stream>>>(adj, whb, whtb, a2b, s1, whf, out);
}